// Round 1
// baseline (243.479 us; speedup 1.0000x reference)
//
#include <hip/hip_runtime.h>

// SSIM loss, fused single-pass separable box filter.
// Layout: 64 images of 512x512 fp32. 11x11 uniform window, zero SAME padding.
//
// Grid: 512 blocks = 64 images x 8 row-bands. Block = 256 threads = 4 waves.
// Each wave (ts = tid>>6) owns a strip of SH=16 output rows across the full
// 512-col width; each lane (tx = tid&63) owns 8 contiguous columns.
// Vertical 11-row window: per-lane register running sums (slide add/sub).
// Horizontal 11-col window: LDS exchange of the 5 column sums + sliding sum.

#define IMG_H 512
#define IMG_W 512
#define N_IMG 64
#define RAD   5
#define NQ    5
#define NSTRIP 4
#define SH    16
#define COL0  16          // offset of logical col 0 inside padded LDS row
#define PW    552         // 16 pad + 512 + 16 pad + 8 slack (keeps 16B align)

#define C1_SSIM 1.0e-4f
#define C2_SSIM 9.0e-4f

__global__ __launch_bounds__(256) void ssim_fused(const float* __restrict__ x,
                                                  const float* __restrict__ y,
                                                  float* __restrict__ acc_out)
{
    __shared__ __align__(16) float ldsV[NQ][NSTRIP][PW];

    const int tx  = threadIdx.x & 63;
    const int ts  = threadIdx.x >> 6;
    const int img = blockIdx.x >> 3;
    const int br  = blockIdx.x & 7;
    const int r0  = br * (NSTRIP * SH) + ts * SH;
    const int c0  = tx * 8;

    // zero the horizontal pad columns (cols [0,16) and [528,544) of each row)
    for (int i = threadIdx.x; i < NQ * NSTRIP * 32; i += 256) {
        int q   = i / (NSTRIP * 32);
        int rem = i - q * (NSTRIP * 32);
        int s   = rem >> 5;
        int p   = rem & 31;
        int col = (p < 16) ? p : (COL0 + IMG_W + p - 16);
        ldsV[q][s][col] = 0.0f;
    }
    // (ordered vs. first reads by the first __syncthreads inside the loop)

    const float* __restrict__ xb = x + (size_t)img * (IMG_H * IMG_W) + c0;
    const float* __restrict__ yb = y + (size_t)img * (IMG_H * IMG_W) + c0;

    float Vx[8], Vy[8], Vxx[8], Vyy[8], Vxy[8];
#pragma unroll
    for (int j = 0; j < 8; ++j) { Vx[j] = 0.f; Vy[j] = 0.f; Vxx[j] = 0.f; Vyy[j] = 0.f; Vxy[j] = 0.f; }

    // add (sgn=+1) or subtract (sgn=-1) one input row into the running sums
    auto accum = [&](int ri, float sgn) {
        const float4* xr = (const float4*)(xb + (size_t)ri * IMG_W);
        const float4* yr = (const float4*)(yb + (size_t)ri * IMG_W);
        float4 x0 = xr[0], x1 = xr[1];
        float4 y0 = yr[0], y1 = yr[1];
        float xs[8] = {x0.x, x0.y, x0.z, x0.w, x1.x, x1.y, x1.z, x1.w};
        float ys[8] = {y0.x, y0.y, y0.z, y0.w, y1.x, y1.y, y1.z, y1.w};
#pragma unroll
        for (int j = 0; j < 8; ++j) {
            float xv = xs[j] * sgn;
            float yv = ys[j] * sgn;
            Vx[j]  += xv;
            Vy[j]  += yv;
            Vxx[j] += xv * xs[j];
            Vyy[j] += yv * ys[j];
            Vxy[j] += xv * ys[j];
        }
    };

    // warm-up: rows [r0-5, r0+4] (invariant: V holds rows ro-5..ro+4 at loop head)
    for (int ri = r0 - RAD; ri < r0 + RAD; ++ri)
        if (ri >= 0 && ri < IMG_H) accum(ri, 1.0f);

    // store 8 running sums (one quantity) to this strip's LDS row
#define STORE_Q(qi, V)                                                        \
    {                                                                         \
        float4* dst = (float4*)&ldsV[qi][ts][COL0 + c0];                      \
        dst[0] = make_float4(V[0], V[1], V[2], V[3]);                         \
        dst[1] = make_float4(V[4], V[5], V[6], V[7]);                         \
    }

    // 11-tap sliding horizontal sums for this lane's 8 output columns
#define HSUM_Q(qi, S)                                                         \
    {                                                                         \
        const float4* src = (const float4*)&ldsV[qi][ts][COL0 + c0 - 8];      \
        float4 a = src[0], b = src[1], c = src[2];                            \
        float4 d = src[3], e = src[4], f = src[5];                            \
        float v[24] = {a.x, a.y, a.z, a.w, b.x, b.y, b.z, b.w,                \
                       c.x, c.y, c.z, c.w, d.x, d.y, d.z, d.w,                \
                       e.x, e.y, e.z, e.w, f.x, f.y, f.z, f.w};               \
        float s = v[3] + v[4] + v[5] + v[6] + v[7] + v[8] + v[9] + v[10] +    \
                  v[11] + v[12] + v[13];                                      \
        S[0] = s;                                                             \
        s += v[14] - v[3];  S[1] = s;                                         \
        s += v[15] - v[4];  S[2] = s;                                         \
        s += v[16] - v[5];  S[3] = s;                                         \
        s += v[17] - v[6];  S[4] = s;                                         \
        s += v[18] - v[7];  S[5] = s;                                         \
        s += v[19] - v[8];  S[6] = s;                                         \
        s += v[20] - v[9];  S[7] = s;                                         \
    }

    const float inv121 = 1.0f / 121.0f;
    float loss = 0.0f;

    for (int ro = r0; ro < r0 + SH; ++ro) {
        // complete the 11-row window: add row ro+5
        int ra = ro + RAD;
        if (ra < IMG_H) accum(ra, 1.0f);

        STORE_Q(0, Vx);
        STORE_Q(1, Vy);
        STORE_Q(2, Vxx);
        STORE_Q(3, Vyy);
        STORE_Q(4, Vxy);
        __syncthreads();

        float Sx[8], Sy[8], Sxx[8], Syy[8], Sxy[8];
        HSUM_Q(0, Sx);
        HSUM_Q(1, Sy);
        HSUM_Q(2, Sxx);
        HSUM_Q(3, Syy);
        HSUM_Q(4, Sxy);

#pragma unroll
        for (int j = 0; j < 8; ++j) {
            float mx  = Sx[j] * inv121;
            float my  = Sy[j] * inv121;
            float mx2 = mx * mx;
            float my2 = my * my;
            float mxy = mx * my;
            float vx  = Sxx[j] * inv121 - mx2;
            float vy  = Syy[j] * inv121 - my2;
            float vxy = Sxy[j] * inv121 - mxy;
            float num = (2.0f * mxy + C1_SSIM) * (2.0f * vxy + C2_SSIM);
            float den = (mx2 + my2 + C1_SSIM) * (vx + vy + C2_SSIM);
            loss += __fdividef(num, den);
        }

        // slide the vertical window: subtract row ro-5 (cache-resident re-read)
        int rs = ro - RAD;
        if (rs >= 0) accum(rs, -1.0f);
        __syncthreads();   // readers done before next iteration's STORE_Q
    }

    // wave-level reduction, one atomic per wave
#pragma unroll
    for (int off = 32; off > 0; off >>= 1)
        loss += __shfl_down(loss, off, 64);
    if (tx == 0) atomicAdd(acc_out, loss);
}

__global__ void ssim_finish(const float* __restrict__ acc, float* __restrict__ out)
{
    out[0] = 1.0f - acc[0] * (1.0f / ((float)N_IMG * IMG_H * IMG_W));
}

extern "C" void kernel_launch(void* const* d_in, const int* in_sizes, int n_in,
                              void* d_out, int out_size, void* d_ws, size_t ws_size,
                              hipStream_t stream) {
    const float* x = (const float*)d_in[0];
    const float* y = (const float*)d_in[1];
    // d_in[2] is the uniform 11x11/121 kernel; its value is compile-time known.
    float* ws = (float*)d_ws;

    hipMemsetAsync(ws, 0, sizeof(float), stream);
    ssim_fused<<<N_IMG * 8, 256, 0, stream>>>(x, y, ws);
    ssim_finish<<<1, 1, 0, stream>>>(ws, (float*)d_out);
}

// Round 2
// 235.610 us; speedup vs baseline: 1.0334x; 1.0334x over previous
//
#include <hip/hip_runtime.h>

// SSIM loss, fused single-pass separable box filter — shuffle-based, LDS-free.
// Layout: 64 images of 512x512 fp32. 11x11 uniform window, zero SAME padding.
//
// Grid: 1024 blocks = 64 images x 16 row-bands. Block = 256 threads = 4
// independent waves (no __syncthreads in the hot loop). Each wave owns a
// strip of SH=8 output rows across the full 512-col width; each lane owns 8
// contiguous columns (2 x float4 coalesced global loads per row per array).
// Vertical 11-row window: per-lane register running sums (slide add/sub; the
// subtracted row re-read is L1/L2-resident, touched 11 rows ago).
// Horizontal 11-col window: 5-float halo from each neighboring lane via
// __shfl (conflict-free ds_bpermute), then an 18-value sliding sum.
// Finalization: per-wave shfl reduce -> atomicAdd; last block (atomic
// counter) writes 1 - mean to d_out. No second kernel.

#define IMG_H 512
#define IMG_W 512
#define N_IMG 64
#define RAD   5
#define SH    8            // output rows per wave
#define NBAND 16           // row bands per image (16 * 4 waves * 8 rows = 512)
#define NBLOCKS (N_IMG * NBAND)

#define C1_SSIM 1.0e-4f
#define C2_SSIM 9.0e-4f

__global__ __launch_bounds__(256) void ssim_fused(const float* __restrict__ x,
                                                  const float* __restrict__ y,
                                                  float* __restrict__ acc,
                                                  unsigned int* __restrict__ cnt,
                                                  float* __restrict__ out)
{
    const int tx  = threadIdx.x & 63;
    const int ts  = threadIdx.x >> 6;
    const int img = blockIdx.x >> 4;          // / NBAND
    const int bnd = blockIdx.x & (NBAND - 1);
    const int r0  = bnd * (4 * SH) + ts * SH;
    const int c0  = tx * 8;

    const float* __restrict__ xb = x + (size_t)img * (IMG_H * IMG_W) + c0;
    const float* __restrict__ yb = y + (size_t)img * (IMG_H * IMG_W) + c0;

    float Vx[8], Vy[8], Vxx[8], Vyy[8], Vxy[8];
#pragma unroll
    for (int j = 0; j < 8; ++j) { Vx[j] = 0.f; Vy[j] = 0.f; Vxx[j] = 0.f; Vyy[j] = 0.f; Vxy[j] = 0.f; }

    // add or subtract one input row into the running vertical sums
    auto accum = [&](int ri, bool add) {
        const float4* xr = (const float4*)(xb + (size_t)ri * IMG_W);
        const float4* yr = (const float4*)(yb + (size_t)ri * IMG_W);
        float4 x0 = xr[0], x1 = xr[1];
        float4 y0 = yr[0], y1 = yr[1];
        float xs[8] = {x0.x, x0.y, x0.z, x0.w, x1.x, x1.y, x1.z, x1.w};
        float ys[8] = {y0.x, y0.y, y0.z, y0.w, y1.x, y1.y, y1.z, y1.w};
        if (add) {
#pragma unroll
            for (int j = 0; j < 8; ++j) {
                Vx[j]  += xs[j];
                Vy[j]  += ys[j];
                Vxx[j] += xs[j] * xs[j];
                Vyy[j] += ys[j] * ys[j];
                Vxy[j] += xs[j] * ys[j];
            }
        } else {
#pragma unroll
            for (int j = 0; j < 8; ++j) {
                Vx[j]  -= xs[j];
                Vy[j]  -= ys[j];
                Vxx[j] -= xs[j] * xs[j];
                Vyy[j] -= ys[j] * ys[j];
                Vxy[j] -= xs[j] * ys[j];
            }
        }
    };

    // 11-tap sliding horizontal sums for this lane's 8 columns.
    // Halo: lane tx-1 supplies cols c0-5..c0-1 (its V[3..7]); lane tx+1
    // supplies cols c0+8..c0+12 (its V[0..4]). Image edges -> zeros (the wave
    // spans the whole row, so lane 0 / lane 63 are the image borders).
    auto hsum = [&](const float (&V)[8], float (&S)[8]) {
        float w[18];
#pragma unroll
        for (int k = 0; k < 5; ++k) {
            float l = __shfl_up(V[3 + k], 1, 64);
            w[k] = (tx == 0) ? 0.f : l;
        }
#pragma unroll
        for (int j = 0; j < 8; ++j) w[5 + j] = V[j];
#pragma unroll
        for (int k = 0; k < 5; ++k) {
            float r = __shfl_down(V[k], 1, 64);
            w[13 + k] = (tx == 63) ? 0.f : r;
        }
        float s = 0.f;
#pragma unroll
        for (int t = 0; t < 11; ++t) s += w[t];
        S[0] = s;
#pragma unroll
        for (int j = 1; j < 8; ++j) { s += w[j + 10] - w[j - 1]; S[j] = s; }
    };

    // warm-up: rows [r0-5, r0+4] (invariant: V holds rows ro-5..ro+4 at loop head)
    for (int ri = r0 - RAD; ri < r0 + RAD; ++ri)
        if (ri >= 0 && ri < IMG_H) accum(ri, true);

    const float inv121 = 1.0f / 121.0f;
    float loss = 0.0f;

    for (int ro = r0; ro < r0 + SH; ++ro) {
        int ra = ro + RAD;
        if (ra < IMG_H) accum(ra, true);

        float Sx[8], Sy[8], Sxx[8], Syy[8], Sxy[8];
        hsum(Vx,  Sx);
        hsum(Vy,  Sy);
        hsum(Vxx, Sxx);
        hsum(Vyy, Syy);
        hsum(Vxy, Sxy);

#pragma unroll
        for (int j = 0; j < 8; ++j) {
            float mx  = Sx[j] * inv121;
            float my  = Sy[j] * inv121;
            float mx2 = mx * mx;
            float my2 = my * my;
            float mxy = mx * my;
            float vx  = Sxx[j] * inv121 - mx2;
            float vy  = Syy[j] * inv121 - my2;
            float vxy = Sxy[j] * inv121 - mxy;
            float num = (2.0f * mxy + C1_SSIM) * (2.0f * vxy + C2_SSIM);
            float den = (mx2 + my2 + C1_SSIM) * (vx + vy + C2_SSIM);
            loss += __fdividef(num, den);
        }

        int rs = ro - RAD;
        if (rs >= 0) accum(rs, false);
    }

    // wave-level reduction, one atomic per wave
#pragma unroll
    for (int off = 32; off > 0; off >>= 1)
        loss += __shfl_down(loss, off, 64);
    if (tx == 0) atomicAdd(acc, loss);

    // last block finalizes (completion counter; atomics are device-scope)
    __syncthreads();                 // all 4 waves' atomicAdds issued
    if (threadIdx.x == 0) {
        __threadfence();
        unsigned int old = atomicAdd(cnt, 1u);
        if (old == NBLOCKS - 1) {
            float total = atomicAdd(acc, 0.0f);   // atomic read, fully ordered
            out[0] = 1.0f - total * (1.0f / ((float)N_IMG * IMG_H * IMG_W));
        }
    }
}

extern "C" void kernel_launch(void* const* d_in, const int* in_sizes, int n_in,
                              void* d_out, int out_size, void* d_ws, size_t ws_size,
                              hipStream_t stream) {
    const float* x = (const float*)d_in[0];
    const float* y = (const float*)d_in[1];
    // d_in[2] is the uniform 11x11/121 kernel; its value is compile-time known.
    float*        acc = (float*)d_ws;
    unsigned int* cnt = (unsigned int*)d_ws + 1;

    hipMemsetAsync(d_ws, 0, 8, stream);   // zero acc + counter
    ssim_fused<<<NBLOCKS, 256, 0, stream>>>(x, y, acc, cnt, (float*)d_out);
}